// Round 16
// baseline (2842.773 us; speedup 1.0000x reference)
//
#include <hip/hip_runtime.h>
#include <hip/hip_bf16.h>
#include <cstdint>

// ---------------------------------------------------------------------------
// KAN 2-layer forward as two bf16 MFMA GEMMs (fp32 output).
// Round-16 (vs r15 pass @793us — occupancy theory confirmed: 2 blocks/CU
// took MfmaUtil 26->43.7%):
//  * Push occupancy further: 3 LDS buffers -> 2 (depth-2 -> ~1.5 pipeline).
//    LDS/block 72->48KB (BN=256) and 48->32KB (BN=128):
//      L0  gemm128<256>: 3 blocks/CU (147KB LDS, 24 waves)
//      L1  gemm128<128>: 4 blocks/CU (128KB LDS, 32 waves — wave-capped)
//    At 3-4 co-resident blocks TLP covers the shorter prefetch flight that
//    depth-2's 3rd buffer was providing (r7's +8% was at 1 block/CU).
//    2-buffer counted schedule (sim-verified, never vmcnt(0) mid-loop):
//      prologue: STAGE(0,0) STAGE(1,1) vmcnt(L) barrier
//      loop kt:  COMPUTE(kt&1) [ends barrier] -> STAGE(kt+2, kt&1)
//                [WAR-safe: buffer fully read pre-barrier] -> vmcnt(L)
//                [2L outstanding -> drains tile kt+1, FIFO] -> barrier
//      tails:    COMPUTE(NT-2) -> vmcnt(0) -> barrier -> COMPUTE(NT-1)
//  * Everything else FROZEN from r15: 0-conflict swizzle both-sides, XCD
//    swizzle, setprio, kperm-576 aux, r3-proven 255.8MB ws, CH=4096 L1.
// ---------------------------------------------------------------------------

typedef __attribute__((ext_vector_type(8))) short short8;
typedef __attribute__((ext_vector_type(4))) short short4v;
typedef __attribute__((ext_vector_type(4))) float f32x4;

#define GLD16(gp, lp)                                                          \
  __builtin_amdgcn_global_load_lds(                                           \
      (const __attribute__((address_space(1))) unsigned int*)(gp),             \
      (__attribute__((address_space(3))) unsigned int*)(lp), 16, 0, 0)

__device__ __forceinline__ unsigned short f2bf(float f) {
  __hip_bfloat16 h = __float2bfloat16(f);
  return *reinterpret_cast<unsigned short*>(&h);
}

__device__ __forceinline__ void basis8(float x, float* w, int& j) {
  float u  = (x + 2.2f) * 2.5f;
  float fj = floorf(u);
  j = (int)fj;
  float t  = u - fj;
  float omt = 1.0f - t;
  float t2 = t * t, t3 = t2 * t;
  w[0] = omt * omt * omt * (1.0f / 6.0f);                              // d==3
  w[1] = (3.0f * t3 - 6.0f * t2 + 4.0f) * (1.0f / 6.0f);               // d==2
  w[2] = (-3.0f * t3 + 3.0f * t2 + 3.0f * t + 1.0f) * (1.0f / 6.0f);   // d==1
  w[3] = t3 * (1.0f / 6.0f);                                           // d==0
}

// ---- pack weights: W[o, kperm(c,i)], kperm = (i/64)*576 + c*64 + (i%64) ----
__global__ void prep_w(const float* __restrict__ coef, const float* __restrict__ sb,
                       const float* __restrict__ sp, const float* __restrict__ mask,
                       __hip_bfloat16* __restrict__ W, int O, int I) {
  long idx = (long)blockIdx.x * blockDim.x + threadIdx.x;
  long total = (long)O * (I >> 2);
  if (idx >= total) return;
  int qtr = I >> 2;
  int iq = (int)(idx % qtr);
  int o  = (int)(idx / qtr);
  int i  = iq << 2;
  size_t oi = (size_t)o * I + i;
  float4 mk4 = *(const float4*)(mask + oi);
  float4 sp4 = *(const float4*)(sp + oi);
  float4 sb4 = *(const float4*)(sb + oi);
  float spm[4] = {sp4.x * mk4.x, sp4.y * mk4.y, sp4.z * mk4.z, sp4.w * mk4.w};
  float cf[4][8];
  const float4* cp = (const float4*)(coef + oi * 8);
#pragma unroll
  for (int e = 0; e < 4; e++) {
    float4 a = cp[e * 2], b = cp[e * 2 + 1];
    cf[e][0] = a.x; cf[e][1] = a.y; cf[e][2] = a.z; cf[e][3] = a.w;
    cf[e][4] = b.x; cf[e][5] = b.y; cf[e][6] = b.z; cf[e][7] = b.w;
  }
  __hip_bfloat16* base = W + (size_t)o * (size_t)(9 * I) + (i >> 6) * 576 + (i & 63);
#pragma unroll
  for (int c = 0; c < 8; c++) {
    short4v pk;
#pragma unroll
    for (int e = 0; e < 4; e++) pk[e] = (short)f2bf(cf[e][c] * spm[e]);
    *(short4v*)(base + c * 64) = pk;
  }
  short4v ps;
  ps[0] = (short)f2bf(sb4.x * mk4.x); ps[1] = (short)f2bf(sb4.y * mk4.y);
  ps[2] = (short)f2bf(sb4.z * mk4.z); ps[3] = (short)f2bf(sb4.w * mk4.w);
  *(short4v*)(base + 8 * 64) = ps;
}

// ---- expand activations: Aug[b, kperm(c,i)], 8 elems/thread ---------------
__global__ void expand_aug(const float* __restrict__ src,
                           __hip_bfloat16* __restrict__ aug,
                           long totalOcts, int I) {
  long idx = (long)blockIdx.x * blockDim.x + threadIdx.x;
  if (idx >= totalOcts) return;
  int  oct = I >> 3;
  int  io = (int)(idx % oct);
  long b  = idx / oct;
  int  i  = io << 3;
  const float* sp = src + b * (size_t)I + i;
  float4 xa = *(const float4*)sp;
  float4 xb = *(const float4*)(sp + 4);
  float xv[8] = {xa.x, xa.y, xa.z, xa.w, xb.x, xb.y, xb.z, xb.w};

  float w[8][4], s[8];
  int   j[8];
#pragma unroll
  for (int e = 0; e < 8; e++) {
    float xe = xv[e];
    s[e] = xe / (1.0f + __expf(-xe));
    basis8(xe, w[e], j[e]);
  }
  __hip_bfloat16* base = aug + b * (size_t)(9 * I) + (i >> 6) * 576 + (i & 63);
#pragma unroll
  for (int c = 0; c < 8; c++) {
    short8 pk;
#pragma unroll
    for (int e = 0; e < 8; e++) {
      int d = j[e] - c;
      float v = 0.0f;
      v = (d == 0) ? w[e][3] : v;
      v = (d == 1) ? w[e][2] : v;
      v = (d == 2) ? w[e][1] : v;
      v = (d == 3) ? w[e][0] : v;
      pk[e] = (short)f2bf(v);
    }
    *(short8*)(base + c * 64) = pk;
  }
  short8 ps;
#pragma unroll
  for (int e = 0; e < 8; e++) ps[e] = (short)f2bf(s[e]);
  *(short8*)(base + 8 * 64) = ps;
}

// ---- 128xBN GEMM, 2-buffer, 3-4 blocks/CU: C = A*Bw^T + bias ---------------
// BM=128, BN 256/128, BK=32, 8 waves 2Mx4N (per-wave 64 x BN/4), 2 buffers.
// LDS: 2 x (8KB + BN*64B) = 48KB (BN=256) / 32KB (BN=128).
// 0-conflict swizzle both-sides: (row,kbyte) at kbyte ^ (((row>>1)&3)<<4).
template <int BN>
__global__ __launch_bounds__(512, 6) void gemm128(
    const __hip_bfloat16* __restrict__ A, const __hip_bfloat16* __restrict__ Bw,
    const float* __restrict__ bias, float* __restrict__ Cout, int N, int K) {
  constexpr int WN   = BN / 4;
  constexpr int NREP = BN / 64;
  constexpr int BUFB = 8192 + BN * 64;
  __shared__ __attribute__((aligned(16))) char lds[2 * BUFB];

  const int t = threadIdx.x;
  const int w = t >> 6, l = t & 63;
  const int wr = w >> 2, wc = w & 3;
  const int lr = l & 15;
  const int kbs = ((l >> 4) * 16) ^ (((lr >> 1) & 3) << 4);

  unsigned nwg = gridDim.x * gridDim.y;
  unsigned lin = blockIdx.y * gridDim.x + blockIdx.x;
  unsigned swz = (lin & 7) * (nwg >> 3) + (lin >> 3);
  unsigned bx = swz % gridDim.x, by = swz / gridDim.x;
  size_t brow = (size_t)by * 128, bcol = (size_t)bx * BN;

  f32x4 acc[4][NREP];
#pragma unroll
  for (int m = 0; m < 4; m++)
#pragma unroll
    for (int n = 0; n < NREP; n++) acc[m][n] = (f32x4){0.f, 0.f, 0.f, 0.f};

  const int srow  = t >> 2;                                     // 0..127
  const int scolb = ((t & 3) * 16) ^ (((srow >> 1) & 3) << 4);
  const __hip_bfloat16* gA0 = A + (brow + srow) * (size_t)K + (scolb >> 1);
  const __hip_bfloat16* gB0 = Bw + (bcol + srow) * (size_t)K + (scolb >> 1);
  const __hip_bfloat16* gB1 = gB0 + (size_t)128 * K;            // BN=256 only

  char* ldsp = (char*)lds;
  const int paOff = (wr * 64 + lr) * 64 + kbs;            // + m*1024 + q*BUFB
  const int pbOff = 8192 + (wc * WN + lr) * 64 + kbs;     // + n*1024 + q*BUFB

  auto STAGE = [&](int kt, int q) {
    char* bp = ldsp + q * BUFB;
    GLD16(gA0 + (kt << 5), bp + w * 1024);
    GLD16(gB0 + (kt << 5), bp + 8192 + w * 1024);
    if constexpr (BN == 256) GLD16(gB1 + (kt << 5), bp + 16384 + w * 1024);
  };
  auto COMPUTE = [&](int q) {
    const char* pa = ldsp + q * BUFB + paOff;
    const char* pb = ldsp + q * BUFB + pbOff;
    short8 bq[NREP], aq[4];
#pragma unroll
    for (int n = 0; n < NREP; n++) bq[n] = *(const short8*)(pb + n * 1024);
#pragma unroll
    for (int m = 0; m < 4; m++) aq[m] = *(const short8*)(pa + m * 1024);
    __builtin_amdgcn_s_setprio(1);
#pragma unroll
    for (int m = 0; m < 4; m++)
#pragma unroll
      for (int n = 0; n < NREP; n++)
        acc[m][n] = __builtin_amdgcn_mfma_f32_16x16x32_bf16(aq[m], bq[n], acc[m][n], 0, 0, 0);
    __builtin_amdgcn_s_setprio(0);
    __builtin_amdgcn_s_barrier();   // all waves' reads of buf q retired
  };
  auto VM0 = [&]() { asm volatile("s_waitcnt vmcnt(0)" ::: "memory"); };
  auto VML = [&]() {
    if constexpr (BN == 256) asm volatile("s_waitcnt vmcnt(3)" ::: "memory");
    else                     asm volatile("s_waitcnt vmcnt(2)" ::: "memory");
  };

  const int NT = K >> 5;   // 288 (L0) / 576 (L1)

  STAGE(0, 0);
  STAGE(1, 1);
  VML();                                  // tile 0 landed (tile 1 in flight)
  __builtin_amdgcn_s_barrier();

  for (int kt = 0; kt < NT - 2; ++kt) {
    COMPUTE(kt & 1);                      // ends with barrier
    STAGE(kt + 2, kt & 1);                // overwrite just-read buffer
    VML();                                // 2L -> L: tile kt+1 landed
    __builtin_amdgcn_s_barrier();         // publish
  }
  COMPUTE((NT - 2) & 1);
  VM0();                                  // tile NT-1 landed
  __builtin_amdgcn_s_barrier();
  COMPUTE((NT - 1) & 1);

  // epilogue
  const int orow = (l >> 4) << 2;
#pragma unroll
  for (int n = 0; n < NREP; n++) {
    size_t col = bcol + (size_t)wc * WN + n * 16 + lr;
    float bv = bias[col];
#pragma unroll
    for (int m = 0; m < 4; m++) {
      size_t row = brow + (size_t)wr * 64 + m * 16 + orow;
#pragma unroll
      for (int r = 0; r < 4; r++)
        Cout[(row + r) * (size_t)N + col] = acc[m][n][r] + bv;
    }
  }
}

// ---------------------------------------------------------------------------
extern "C" void kernel_launch(void* const* d_in, const int* in_sizes, int n_in,
                              void* d_out, int out_size, void* d_ws, size_t ws_size,
                              hipStream_t stream) {
  const float* x     = (const float*)d_in[0];
  const float* coef0 = (const float*)d_in[1];
  const float* sb0   = (const float*)d_in[2];
  const float* sp0   = (const float*)d_in[3];
  const float* mask0 = (const float*)d_in[4];
  const float* bias0 = (const float*)d_in[5];
  const float* coef1 = (const float*)d_in[6];
  const float* sb1   = (const float*)d_in[7];
  const float* sp1   = (const float*)d_in[8];
  const float* mask1 = (const float*)d_in[9];
  const float* bias1 = (const float*)d_in[10];
  float* out = (float*)d_out;

  const int B = 8192, D0 = 1024, D1 = 2048, D2 = 1024;
  const int K0 = 9 * D0;   // 9216
  const int K1 = 9 * D1;   // 18432
  const int CH = 4096;     // L1 batch chunk

  // ws (255,852,544 B total — r3-PROVEN):
  //   h1  [0, 67108864) | W [67108864, 104857600) | Aug [104857600, +151MB)
  char* ws = (char*)d_ws;
  float*          h1  = (float*)ws;
  __hip_bfloat16* W   = (__hip_bfloat16*)(ws + (size_t)67108864);
  __hip_bfloat16* Aug = (__hip_bfloat16*)(ws + (size_t)104857600);

  // ---- layer 0: full batch ----
  {
    long nt = (long)D1 * (D0 / 4);
    prep_w<<<(unsigned)((nt + 255) / 256), 256, 0, stream>>>(coef0, sb0, sp0, mask0, W, D1, D0);
    long no = (long)B * (D0 / 8);
    expand_aug<<<(unsigned)((no + 255) / 256), 256, 0, stream>>>(x, Aug, no, D0);
    dim3 g0(D1 / 256, B / 128);   // (8, 64) = 512 blocks, 3/CU
    gemm128<256><<<g0, 512, 0, stream>>>(Aug, W, bias0, h1, D1, K0);
  }

  // ---- layer 1: 2 chunks of 4096, each on the FULL GPU ----
  {
    long nt = (long)D2 * (D1 / 4);
    prep_w<<<(unsigned)((nt + 255) / 256), 256, 0, stream>>>(coef1, sb1, sp1, mask1, W, D2, D1);
    for (int ch = 0; ch < B / CH; ch++) {
      long no = (long)CH * (D1 / 8);
      expand_aug<<<(unsigned)((no + 255) / 256), 256, 0, stream>>>(
          h1 + (size_t)ch * CH * D1, Aug, no, D1);
      dim3 g1(D2 / 128, CH / 128);   // (8, 32) = 256 blocks, 4/CU
      gemm128<128><<<g1, 512, 0, stream>>>(Aug, W, bias1,
                                           out + (size_t)ch * CH * D2, D2, K1);
    }
  }
}

// Round 17
// 859.706 us; speedup vs baseline: 3.3067x; 3.3067x over previous
//
#include <hip/hip_runtime.h>
#include <hip/hip_bf16.h>
#include <cstdint>

// ---------------------------------------------------------------------------
// KAN 2-layer forward as two bf16 MFMA GEMMs (fp32 output).
// Round-17 (vs r15 @793us best; r16 spill root-caused: (512,6) budget=85 <
// acc64+operands for BN=256 -> accumulator scratch-spill, 8.3GB writes):
//  * L0 GEMM now BN=128 (acc[4][2]=32 regs; live ~76 <= 85) with
//    __launch_bounds__(512,6): grid (16,64)=1024 blocks = 3 blocks/CU
//    (LDS 3x16KB=48KB). Next notch of the r15 occupancy lever (1->2 blocks
//    was +24%). Only gemm128<128> is instantiated. Schedule/swizzles are
//    r15-verbatim (3-buf depth-2, counted vmcnt, 0-conflict swizzle
//    both-sides, XCD swizzle, setprio).
//  * L1 path unchanged from r15 (CH=4096, grid (8,32)).
//  * prep_w+expand merged: prep0 = {W0-pack, expand0}, prep1 = {W1-pack,
//    expand1-chunk0}; both segment counts 256-divisible (no block-internal
//    divergence). 8 -> 6 dispatches.
//  * ws = r3-proven 255,852,544 B: h1 | W | Aug region (unchanged).
// Spill tripwire for post-mortem: gemm VGPR_Count must be <=84 and
// WRITE_SIZE ~67MB; anything else = spill -> revert to (512,4)+BN=256.
// ---------------------------------------------------------------------------

typedef __attribute__((ext_vector_type(8))) short short8;
typedef __attribute__((ext_vector_type(4))) short short4v;
typedef __attribute__((ext_vector_type(4))) float f32x4;

#define GLD16(gp, lp)                                                          \
  __builtin_amdgcn_global_load_lds(                                           \
      (const __attribute__((address_space(1))) unsigned int*)(gp),             \
      (__attribute__((address_space(3))) unsigned int*)(lp), 16, 0, 0)

__device__ __forceinline__ unsigned short f2bf(float f) {
  __hip_bfloat16 h = __float2bfloat16(f);
  return *reinterpret_cast<unsigned short*>(&h);
}

__device__ __forceinline__ void basis8(float x, float* w, int& j) {
  float u  = (x + 2.2f) * 2.5f;
  float fj = floorf(u);
  j = (int)fj;
  float t  = u - fj;
  float omt = 1.0f - t;
  float t2 = t * t, t3 = t2 * t;
  w[0] = omt * omt * omt * (1.0f / 6.0f);                              // d==3
  w[1] = (3.0f * t3 - 6.0f * t2 + 4.0f) * (1.0f / 6.0f);               // d==2
  w[2] = (-3.0f * t3 + 3.0f * t2 + 3.0f * t + 1.0f) * (1.0f / 6.0f);   // d==1
  w[3] = t3 * (1.0f / 6.0f);                                           // d==0
}

// ---- prep_w item: W[o, kperm(c,i)], kperm = (i/64)*576 + c*64 + (i%64) ----
__device__ __forceinline__ void prep_w_item(
    long idx, const float* __restrict__ coef, const float* __restrict__ sb,
    const float* __restrict__ sp, const float* __restrict__ mask,
    __hip_bfloat16* __restrict__ W, int I) {
  int qtr = I >> 2;
  int iq = (int)(idx % qtr);
  int o  = (int)(idx / qtr);
  int i  = iq << 2;
  size_t oi = (size_t)o * I + i;
  float4 mk4 = *(const float4*)(mask + oi);
  float4 sp4 = *(const float4*)(sp + oi);
  float4 sb4 = *(const float4*)(sb + oi);
  float spm[4] = {sp4.x * mk4.x, sp4.y * mk4.y, sp4.z * mk4.z, sp4.w * mk4.w};
  float cf[4][8];
  const float4* cp = (const float4*)(coef + oi * 8);
#pragma unroll
  for (int e = 0; e < 4; e++) {
    float4 a = cp[e * 2], b = cp[e * 2 + 1];
    cf[e][0] = a.x; cf[e][1] = a.y; cf[e][2] = a.z; cf[e][3] = a.w;
    cf[e][4] = b.x; cf[e][5] = b.y; cf[e][6] = b.z; cf[e][7] = b.w;
  }
  __hip_bfloat16* base = W + (size_t)o * (size_t)(9 * I) + (i >> 6) * 576 + (i & 63);
#pragma unroll
  for (int c = 0; c < 8; c++) {
    short4v pk;
#pragma unroll
    for (int e = 0; e < 4; e++) pk[e] = (short)f2bf(cf[e][c] * spm[e]);
    *(short4v*)(base + c * 64) = pk;
  }
  short4v ps;
  ps[0] = (short)f2bf(sb4.x * mk4.x); ps[1] = (short)f2bf(sb4.y * mk4.y);
  ps[2] = (short)f2bf(sb4.z * mk4.z); ps[3] = (short)f2bf(sb4.w * mk4.w);
  *(short4v*)(base + 8 * 64) = ps;
}

// ---- expand item: Aug[b, kperm(c,i)], 8 elems ------------------------------
__device__ __forceinline__ void expand_item(
    long idx, const float* __restrict__ src, __hip_bfloat16* __restrict__ aug,
    int I) {
  int  oct = I >> 3;
  int  io = (int)(idx % oct);
  long b  = idx / oct;
  int  i  = io << 3;
  const float* sp = src + b * (size_t)I + i;
  float4 xa = *(const float4*)sp;
  float4 xb = *(const float4*)(sp + 4);
  float xv[8] = {xa.x, xa.y, xa.z, xa.w, xb.x, xb.y, xb.z, xb.w};

  float w[8][4], s[8];
  int   j[8];
#pragma unroll
  for (int e = 0; e < 8; e++) {
    float xe = xv[e];
    s[e] = xe / (1.0f + __expf(-xe));
    basis8(xe, w[e], j[e]);
  }
  __hip_bfloat16* base = aug + b * (size_t)(9 * I) + (i >> 6) * 576 + (i & 63);
#pragma unroll
  for (int c = 0; c < 8; c++) {
    short8 pk;
#pragma unroll
    for (int e = 0; e < 8; e++) {
      int d = j[e] - c;
      float v = 0.0f;
      v = (d == 0) ? w[e][3] : v;
      v = (d == 1) ? w[e][2] : v;
      v = (d == 2) ? w[e][1] : v;
      v = (d == 3) ? w[e][0] : v;
      pk[e] = (short)f2bf(v);
    }
    *(short8*)(base + c * 64) = pk;
  }
  short8 ps;
#pragma unroll
  for (int e = 0; e < 8; e++) ps[e] = (short)f2bf(s[e]);
  *(short8*)(base + 8 * 64) = ps;
}

// ---- merged prep: {W-pack items} then {expand octets} ----------------------
// nW and expand-octet counts are both multiples of 256 -> block-uniform path.
__global__ void prep_merge(
    const float* __restrict__ coef, const float* __restrict__ sb,
    const float* __restrict__ sp, const float* __restrict__ mask,
    __hip_bfloat16* __restrict__ W, int IW, long nW,
    const float* __restrict__ xsrc, __hip_bfloat16* __restrict__ aug,
    int IX, long nX) {
  long idx = (long)blockIdx.x * blockDim.x + threadIdx.x;
  if (idx < nW)            prep_w_item(idx, coef, sb, sp, mask, W, IW);
  else if (idx < nW + nX)  expand_item(idx - nW, xsrc, aug, IX);
}

// ---- expand1 standalone (chunk 1) ------------------------------------------
__global__ void expand_aug(const float* __restrict__ src,
                           __hip_bfloat16* __restrict__ aug,
                           long totalOcts, int I) {
  long idx = (long)blockIdx.x * blockDim.x + threadIdx.x;
  if (idx >= totalOcts) return;
  expand_item(idx, src, aug, I);
}

// ---- 128x128 GEMM, 3 blocks/CU: C = A*Bw^T + bias, fp32 out ----------------
// BM=128, BN=128, BK=32, 8 waves 2Mx4N (per-wave 64x32, acc[4][2]=32 regs),
// 3 buffers (16KB each, 48KB total). r15 schedule verbatim: depth-2 prefetch,
// counted vmcnt (VML=2, VM2L=4, tails 2/0), 0-conflict swizzle both-sides,
// XCD bijective swizzle, setprio. __launch_bounds__(512,6) -> 3 blocks/CU
// (budget 85 VGPR; live ~76).
template <int BN>
__global__ __launch_bounds__(512, 6) void gemm128(
    const __hip_bfloat16* __restrict__ A, const __hip_bfloat16* __restrict__ Bw,
    const float* __restrict__ bias, float* __restrict__ Cout, int N, int K) {
  constexpr int WN   = BN / 4;
  constexpr int NREP = BN / 64;
  constexpr int BUFB = 8192 + BN * 64;
  __shared__ __attribute__((aligned(16))) char lds[3 * BUFB];

  const int t = threadIdx.x;
  const int w = t >> 6, l = t & 63;
  const int wr = w >> 2, wc = w & 3;
  const int lr = l & 15;
  const int kbs = ((l >> 4) * 16) ^ (((lr >> 1) & 3) << 4);

  unsigned nwg = gridDim.x * gridDim.y;
  unsigned lin = blockIdx.y * gridDim.x + blockIdx.x;
  unsigned swz = (lin & 7) * (nwg >> 3) + (lin >> 3);
  unsigned bx = swz % gridDim.x, by = swz / gridDim.x;
  size_t brow = (size_t)by * 128, bcol = (size_t)bx * BN;

  f32x4 acc[4][NREP];
#pragma unroll
  for (int m = 0; m < 4; m++)
#pragma unroll
    for (int n = 0; n < NREP; n++) acc[m][n] = (f32x4){0.f, 0.f, 0.f, 0.f};

  const int srow  = t >> 2;                                     // 0..127
  const int scolb = ((t & 3) * 16) ^ (((srow >> 1) & 3) << 4);
  const __hip_bfloat16* gA0 = A + (brow + srow) * (size_t)K + (scolb >> 1);
  const __hip_bfloat16* gB0 = Bw + (bcol + srow) * (size_t)K + (scolb >> 1);
  const __hip_bfloat16* gB1 = gB0 + (size_t)128 * K;            // BN=256 only

  char* ldsp = (char*)lds;
  const int paOff = (wr * 64 + lr) * 64 + kbs;            // + m*1024 + q*BUFB
  const int pbOff = 8192 + (wc * WN + lr) * 64 + kbs;     // + n*1024 + q*BUFB

  auto STAGE = [&](int kt, int q) {
    char* bp = ldsp + q * BUFB;
    GLD16(gA0 + (kt << 5), bp + w * 1024);
    GLD16(gB0 + (kt << 5), bp + 8192 + w * 1024);
    if constexpr (BN == 256) GLD16(gB1 + (kt << 5), bp + 16384 + w * 1024);
  };
  auto COMPUTE = [&](int q) {
    const char* pa = ldsp + q * BUFB + paOff;
    const char* pb = ldsp + q * BUFB + pbOff;
    short8 bq[NREP], aq[4];
#pragma unroll
    for (int n = 0; n < NREP; n++) bq[n] = *(const short8*)(pb + n * 1024);
#pragma unroll
    for (int m = 0; m < 4; m++) aq[m] = *(const short8*)(pa + m * 1024);
    __builtin_amdgcn_s_setprio(1);
#pragma unroll
    for (int m = 0; m < 4; m++)
#pragma unroll
      for (int n = 0; n < NREP; n++)
        acc[m][n] = __builtin_amdgcn_mfma_f32_16x16x32_bf16(aq[m], bq[n], acc[m][n], 0, 0, 0);
    __builtin_amdgcn_s_setprio(0);
    __builtin_amdgcn_s_barrier();   // all waves' reads of buf q retired
  };
  auto VM0 = [&]() { asm volatile("s_waitcnt vmcnt(0)" ::: "memory"); };
  auto VML = [&]() {
    if constexpr (BN == 256) asm volatile("s_waitcnt vmcnt(3)" ::: "memory");
    else                     asm volatile("s_waitcnt vmcnt(2)" ::: "memory");
  };
  auto VM2L = [&]() {
    if constexpr (BN == 256) asm volatile("s_waitcnt vmcnt(6)" ::: "memory");
    else                     asm volatile("s_waitcnt vmcnt(4)" ::: "memory");
  };

  const int NT = K >> 5;   // 288 (L0) / 576 (L1)

  STAGE(0, 0);
  STAGE(1, 1);
  VML();                                  // tile 0 landed
  __builtin_amdgcn_s_barrier();

  int q0 = 0;
  for (int kt = 0; kt < NT - 2; ++kt) {
    int q2 = q0 + 2; if (q2 >= 3) q2 -= 3;
    STAGE(kt + 2, q2);                    // buf of tile kt-1 (reads done)
    VM2L();                               // oldest L drained
    __builtin_amdgcn_s_barrier();         // publish
    COMPUTE(q0);
    q0 = (q0 == 2) ? 0 : q0 + 1;
  }
  VML();                                  // tile NT-2 landed
  __builtin_amdgcn_s_barrier();
  COMPUTE(q0);
  q0 = (q0 == 2) ? 0 : q0 + 1;
  VM0();                                  // tile NT-1 landed
  __builtin_amdgcn_s_barrier();
  COMPUTE(q0);

  // epilogue
  const int orow = (l >> 4) << 2;
#pragma unroll
  for (int n = 0; n < NREP; n++) {
    size_t col = bcol + (size_t)wc * WN + n * 16 + lr;
    float bv = bias[col];
#pragma unroll
    for (int m = 0; m < 4; m++) {
      size_t row = brow + (size_t)wr * 64 + m * 16 + orow;
#pragma unroll
      for (int r = 0; r < 4; r++)
        Cout[(row + r) * (size_t)N + col] = acc[m][n][r] + bv;
    }
  }
}

// ---------------------------------------------------------------------------
extern "C" void kernel_launch(void* const* d_in, const int* in_sizes, int n_in,
                              void* d_out, int out_size, void* d_ws, size_t ws_size,
                              hipStream_t stream) {
  const float* x     = (const float*)d_in[0];
  const float* coef0 = (const float*)d_in[1];
  const float* sb0   = (const float*)d_in[2];
  const float* sp0   = (const float*)d_in[3];
  const float* mask0 = (const float*)d_in[4];
  const float* bias0 = (const float*)d_in[5];
  const float* coef1 = (const float*)d_in[6];
  const float* sb1   = (const float*)d_in[7];
  const float* sp1   = (const float*)d_in[8];
  const float* mask1 = (const float*)d_in[9];
  const float* bias1 = (const float*)d_in[10];
  float* out = (float*)d_out;

  const int B = 8192, D0 = 1024, D1 = 2048, D2 = 1024;
  const int K0 = 9 * D0;   // 9216
  const int K1 = 9 * D1;   // 18432
  const int CH = 4096;     // L1 batch chunk

  // ws (255,852,544 B total — r3-PROVEN):
  //   h1  [0, 67108864) | W [67108864, 104857600) | Aug [104857600, +151MB)
  char* ws = (char*)d_ws;
  float*          h1  = (float*)ws;
  __hip_bfloat16* W   = (__hip_bfloat16*)(ws + (size_t)67108864);
  __hip_bfloat16* Aug = (__hip_bfloat16*)(ws + (size_t)104857600);

  const long nW0 = (long)D1 * (D0 / 4);   // 524288
  const long nX0 = (long)B * (D0 / 8);    // 1048576
  const long nW1 = (long)D2 * (D1 / 4);   // 524288
  const long nX1 = (long)CH * (D1 / 8);   // 1048576

  // ---- layer 0: merged prep (W0 + Aug0), then GEMM at 3 blocks/CU ----
  prep_merge<<<(unsigned)((nW0 + nX0) / 256), 256, 0, stream>>>(
      coef0, sb0, sp0, mask0, W, D0, nW0, x, Aug, D0, nX0);
  {
    dim3 g0(D1 / 128, B / 128);   // (16, 64) = 1024 blocks, 3/CU
    gemm128<128><<<g0, 512, 0, stream>>>(Aug, W, bias0, h1, D1, K0);
  }

  // ---- layer 1: merged prep (W1 + Aug1 chunk0), GEMM, chunk1 ----
  prep_merge<<<(unsigned)((nW1 + nX1) / 256), 256, 0, stream>>>(
      coef1, sb1, sp1, mask1, W, D1, nW1, h1, Aug, D1, nX1);
  {
    dim3 g1(D2 / 128, CH / 128);   // (8, 32) = 256 blocks
    gemm128<128><<<g1, 512, 0, stream>>>(Aug, W, bias1, out, D2, K1);
  }
  expand_aug<<<(unsigned)(nX1 / 256), 256, 0, stream>>>(
      h1 + (size_t)CH * D1, Aug, nX1, D1);
  {
    dim3 g1(D2 / 128, CH / 128);
    gemm128<128><<<g1, 512, 0, stream>>>(Aug, W, bias1,
                                         out + (size_t)CH * D2, D2, K1);
  }
}

// Round 18
// 789.900 us; speedup vs baseline: 3.5989x; 1.0884x over previous
//
#include <hip/hip_runtime.h>
#include <hip/hip_bf16.h>
#include <cstdint>

// ---------------------------------------------------------------------------
// KAN 2-layer forward as two bf16 MFMA GEMMs (fp32 output).
// Round-18 = r15 (best, 793us) + r17's prep_merge only:
//  * GEMMs r15-VERBATIM: gemm128 BM=128, 3-buf depth-2, counted vmcnt,
//    0-conflict swizzle both-sides, XCD swizzle, setprio,
//    __launch_bounds__(512,4) -> 2 blocks/CU (r16/r17 proved: (512,6)
//    spills BN=256 and the small-tile alternative loses more to traffic
//    than 3 blocks/CU gains; L1's 256-block grid is 1 block/CU anyway).
//    L0: gemm128<256> grid (8,64); L1: gemm128<128> grid (8,32) x2 chunks.
//  * prep_merge: {W0-pack + expand0} and {W1-pack + expand1-chunk0} each
//    one dispatch; expand1-chunk1 standalone. 8 -> 6 dispatches.
//  * ws = r3-proven 255,852,544 B: h1 | W | Aug region. CH=4096.
// r17 post-mortem: occupancy lever exhausted; L0 near traffic-bound
// (FETCH 665MB @2.3TB/s ~ dur); aux ~130us ~ traffic-ideal.
// ---------------------------------------------------------------------------

typedef __attribute__((ext_vector_type(8))) short short8;
typedef __attribute__((ext_vector_type(4))) short short4v;
typedef __attribute__((ext_vector_type(4))) float f32x4;

#define GLD16(gp, lp)                                                          \
  __builtin_amdgcn_global_load_lds(                                           \
      (const __attribute__((address_space(1))) unsigned int*)(gp),             \
      (__attribute__((address_space(3))) unsigned int*)(lp), 16, 0, 0)

__device__ __forceinline__ unsigned short f2bf(float f) {
  __hip_bfloat16 h = __float2bfloat16(f);
  return *reinterpret_cast<unsigned short*>(&h);
}

__device__ __forceinline__ void basis8(float x, float* w, int& j) {
  float u  = (x + 2.2f) * 2.5f;
  float fj = floorf(u);
  j = (int)fj;
  float t  = u - fj;
  float omt = 1.0f - t;
  float t2 = t * t, t3 = t2 * t;
  w[0] = omt * omt * omt * (1.0f / 6.0f);                              // d==3
  w[1] = (3.0f * t3 - 6.0f * t2 + 4.0f) * (1.0f / 6.0f);               // d==2
  w[2] = (-3.0f * t3 + 3.0f * t2 + 3.0f * t + 1.0f) * (1.0f / 6.0f);   // d==1
  w[3] = t3 * (1.0f / 6.0f);                                           // d==0
}

// ---- prep_w item: W[o, kperm(c,i)], kperm = (i/64)*576 + c*64 + (i%64) ----
__device__ __forceinline__ void prep_w_item(
    long idx, const float* __restrict__ coef, const float* __restrict__ sb,
    const float* __restrict__ sp, const float* __restrict__ mask,
    __hip_bfloat16* __restrict__ W, int I) {
  int qtr = I >> 2;
  int iq = (int)(idx % qtr);
  int o  = (int)(idx / qtr);
  int i  = iq << 2;
  size_t oi = (size_t)o * I + i;
  float4 mk4 = *(const float4*)(mask + oi);
  float4 sp4 = *(const float4*)(sp + oi);
  float4 sb4 = *(const float4*)(sb + oi);
  float spm[4] = {sp4.x * mk4.x, sp4.y * mk4.y, sp4.z * mk4.z, sp4.w * mk4.w};
  float cf[4][8];
  const float4* cp = (const float4*)(coef + oi * 8);
#pragma unroll
  for (int e = 0; e < 4; e++) {
    float4 a = cp[e * 2], b = cp[e * 2 + 1];
    cf[e][0] = a.x; cf[e][1] = a.y; cf[e][2] = a.z; cf[e][3] = a.w;
    cf[e][4] = b.x; cf[e][5] = b.y; cf[e][6] = b.z; cf[e][7] = b.w;
  }
  __hip_bfloat16* base = W + (size_t)o * (size_t)(9 * I) + (i >> 6) * 576 + (i & 63);
#pragma unroll
  for (int c = 0; c < 8; c++) {
    short4v pk;
#pragma unroll
    for (int e = 0; e < 4; e++) pk[e] = (short)f2bf(cf[e][c] * spm[e]);
    *(short4v*)(base + c * 64) = pk;
  }
  short4v ps;
  ps[0] = (short)f2bf(sb4.x * mk4.x); ps[1] = (short)f2bf(sb4.y * mk4.y);
  ps[2] = (short)f2bf(sb4.z * mk4.z); ps[3] = (short)f2bf(sb4.w * mk4.w);
  *(short4v*)(base + 8 * 64) = ps;
}

// ---- expand item: Aug[b, kperm(c,i)], 8 elems ------------------------------
__device__ __forceinline__ void expand_item(
    long idx, const float* __restrict__ src, __hip_bfloat16* __restrict__ aug,
    int I) {
  int  oct = I >> 3;
  int  io = (int)(idx % oct);
  long b  = idx / oct;
  int  i  = io << 3;
  const float* sp = src + b * (size_t)I + i;
  float4 xa = *(const float4*)sp;
  float4 xb = *(const float4*)(sp + 4);
  float xv[8] = {xa.x, xa.y, xa.z, xa.w, xb.x, xb.y, xb.z, xb.w};

  float w[8][4], s[8];
  int   j[8];
#pragma unroll
  for (int e = 0; e < 8; e++) {
    float xe = xv[e];
    s[e] = xe / (1.0f + __expf(-xe));
    basis8(xe, w[e], j[e]);
  }
  __hip_bfloat16* base = aug + b * (size_t)(9 * I) + (i >> 6) * 576 + (i & 63);
#pragma unroll
  for (int c = 0; c < 8; c++) {
    short8 pk;
#pragma unroll
    for (int e = 0; e < 8; e++) {
      int d = j[e] - c;
      float v = 0.0f;
      v = (d == 0) ? w[e][3] : v;
      v = (d == 1) ? w[e][2] : v;
      v = (d == 2) ? w[e][1] : v;
      v = (d == 3) ? w[e][0] : v;
      pk[e] = (short)f2bf(v);
    }
    *(short8*)(base + c * 64) = pk;
  }
  short8 ps;
#pragma unroll
  for (int e = 0; e < 8; e++) ps[e] = (short)f2bf(s[e]);
  *(short8*)(base + 8 * 64) = ps;
}

// ---- merged prep: {W-pack items} then {expand octets} ----------------------
__global__ void prep_merge(
    const float* __restrict__ coef, const float* __restrict__ sb,
    const float* __restrict__ sp, const float* __restrict__ mask,
    __hip_bfloat16* __restrict__ W, int IW, long nW,
    const float* __restrict__ xsrc, __hip_bfloat16* __restrict__ aug,
    int IX, long nX) {
  long idx = (long)blockIdx.x * blockDim.x + threadIdx.x;
  if (idx < nW)            prep_w_item(idx, coef, sb, sp, mask, W, IW);
  else if (idx < nW + nX)  expand_item(idx - nW, xsrc, aug, IX);
}

__global__ void expand_aug(const float* __restrict__ src,
                           __hip_bfloat16* __restrict__ aug,
                           long totalOcts, int I) {
  long idx = (long)blockIdx.x * blockDim.x + threadIdx.x;
  if (idx >= totalOcts) return;
  expand_item(idx, src, aug, I);
}

// ---- 128xBN GEMM (r15-verbatim): C = A*Bw^T + bias, fp32 out ---------------
// BM=128, BN 256/128, BK=32, 8 waves 2Mx4N (per-wave 64 x BN/4), 3 buffers.
// LDS: 3 x (8KB + BN*64B) = 72/48KB -> 2 blocks/CU (launch_bounds 512,4).
// Depth-2 prefetch, counted vmcnt; 0-conflict swizzle both-sides.
template <int BN>
__global__ __launch_bounds__(512, 4) void gemm128(
    const __hip_bfloat16* __restrict__ A, const __hip_bfloat16* __restrict__ Bw,
    const float* __restrict__ bias, float* __restrict__ Cout, int N, int K) {
  constexpr int WN   = BN / 4;
  constexpr int NREP = BN / 64;
  constexpr int BUFB = 8192 + BN * 64;
  __shared__ __attribute__((aligned(16))) char lds[3 * BUFB];

  const int t = threadIdx.x;
  const int w = t >> 6, l = t & 63;
  const int wr = w >> 2, wc = w & 3;
  const int lr = l & 15;
  const int kbs = ((l >> 4) * 16) ^ (((lr >> 1) & 3) << 4);

  unsigned nwg = gridDim.x * gridDim.y;
  unsigned lin = blockIdx.y * gridDim.x + blockIdx.x;
  unsigned swz = (lin & 7) * (nwg >> 3) + (lin >> 3);
  unsigned bx = swz % gridDim.x, by = swz / gridDim.x;
  size_t brow = (size_t)by * 128, bcol = (size_t)bx * BN;

  f32x4 acc[4][NREP];
#pragma unroll
  for (int m = 0; m < 4; m++)
#pragma unroll
    for (int n = 0; n < NREP; n++) acc[m][n] = (f32x4){0.f, 0.f, 0.f, 0.f};

  const int srow  = t >> 2;                                     // 0..127
  const int scolb = ((t & 3) * 16) ^ (((srow >> 1) & 3) << 4);
  const __hip_bfloat16* gA0 = A + (brow + srow) * (size_t)K + (scolb >> 1);
  const __hip_bfloat16* gB0 = Bw + (bcol + srow) * (size_t)K + (scolb >> 1);
  const __hip_bfloat16* gB1 = gB0 + (size_t)128 * K;            // BN=256 only

  char* ldsp = (char*)lds;
  const int paOff = (wr * 64 + lr) * 64 + kbs;            // + m*1024 + q*BUFB
  const int pbOff = 8192 + (wc * WN + lr) * 64 + kbs;     // + n*1024 + q*BUFB

  auto STAGE = [&](int kt, int q) {
    char* bp = ldsp + q * BUFB;
    GLD16(gA0 + (kt << 5), bp + w * 1024);
    GLD16(gB0 + (kt << 5), bp + 8192 + w * 1024);
    if constexpr (BN == 256) GLD16(gB1 + (kt << 5), bp + 16384 + w * 1024);
  };
  auto COMPUTE = [&](int q) {
    const char* pa = ldsp + q * BUFB + paOff;
    const char* pb = ldsp + q * BUFB + pbOff;
    short8 bq[NREP], aq[4];
#pragma unroll
    for (int n = 0; n < NREP; n++) bq[n] = *(const short8*)(pb + n * 1024);
#pragma unroll
    for (int m = 0; m < 4; m++) aq[m] = *(const short8*)(pa + m * 1024);
    __builtin_amdgcn_s_setprio(1);
#pragma unroll
    for (int m = 0; m < 4; m++)
#pragma unroll
      for (int n = 0; n < NREP; n++)
        acc[m][n] = __builtin_amdgcn_mfma_f32_16x16x32_bf16(aq[m], bq[n], acc[m][n], 0, 0, 0);
    __builtin_amdgcn_s_setprio(0);
    __builtin_amdgcn_s_barrier();   // all waves' reads of buf q retired
  };
  auto VM0 = [&]() { asm volatile("s_waitcnt vmcnt(0)" ::: "memory"); };
  auto VML = [&]() {
    if constexpr (BN == 256) asm volatile("s_waitcnt vmcnt(3)" ::: "memory");
    else                     asm volatile("s_waitcnt vmcnt(2)" ::: "memory");
  };
  auto VM2L = [&]() {
    if constexpr (BN == 256) asm volatile("s_waitcnt vmcnt(6)" ::: "memory");
    else                     asm volatile("s_waitcnt vmcnt(4)" ::: "memory");
  };

  const int NT = K >> 5;   // 288 (L0) / 576 (L1)

  STAGE(0, 0);
  STAGE(1, 1);
  VML();                                  // tile 0 landed
  __builtin_amdgcn_s_barrier();

  int q0 = 0;
  for (int kt = 0; kt < NT - 2; ++kt) {
    int q2 = q0 + 2; if (q2 >= 3) q2 -= 3;
    STAGE(kt + 2, q2);                    // buf of tile kt-1 (reads done)
    VM2L();                               // oldest L drained: tile kt landed
    __builtin_amdgcn_s_barrier();         // publish
    COMPUTE(q0);
    q0 = (q0 == 2) ? 0 : q0 + 1;
  }
  VML();                                  // tile NT-2 landed
  __builtin_amdgcn_s_barrier();
  COMPUTE(q0);
  q0 = (q0 == 2) ? 0 : q0 + 1;
  VM0();                                  // tile NT-1 landed
  __builtin_amdgcn_s_barrier();
  COMPUTE(q0);

  // epilogue
  const int orow = (l >> 4) << 2;
#pragma unroll
  for (int n = 0; n < NREP; n++) {
    size_t col = bcol + (size_t)wc * WN + n * 16 + lr;
    float bv = bias[col];
#pragma unroll
    for (int m = 0; m < 4; m++) {
      size_t row = brow + (size_t)wr * 64 + m * 16 + orow;
#pragma unroll
      for (int r = 0; r < 4; r++)
        Cout[(row + r) * (size_t)N + col] = acc[m][n][r] + bv;
    }
  }
}

// ---------------------------------------------------------------------------
extern "C" void kernel_launch(void* const* d_in, const int* in_sizes, int n_in,
                              void* d_out, int out_size, void* d_ws, size_t ws_size,
                              hipStream_t stream) {
  const float* x     = (const float*)d_in[0];
  const float* coef0 = (const float*)d_in[1];
  const float* sb0   = (const float*)d_in[2];
  const float* sp0   = (const float*)d_in[3];
  const float* mask0 = (const float*)d_in[4];
  const float* bias0 = (const float*)d_in[5];
  const float* coef1 = (const float*)d_in[6];
  const float* sb1   = (const float*)d_in[7];
  const float* sp1   = (const float*)d_in[8];
  const float* mask1 = (const float*)d_in[9];
  const float* bias1 = (const float*)d_in[10];
  float* out = (float*)d_out;

  const int B = 8192, D0 = 1024, D1 = 2048, D2 = 1024;
  const int K0 = 9 * D0;   // 9216
  const int K1 = 9 * D1;   // 18432
  const int CH = 4096;     // L1 batch chunk

  // ws (255,852,544 B total — r3-PROVEN):
  //   h1  [0, 67108864) | W [67108864, 104857600) | Aug [104857600, +151MB)
  char* ws = (char*)d_ws;
  float*          h1  = (float*)ws;
  __hip_bfloat16* W   = (__hip_bfloat16*)(ws + (size_t)67108864);
  __hip_bfloat16* Aug = (__hip_bfloat16*)(ws + (size_t)104857600);

  const long nW0 = (long)D1 * (D0 / 4);   // 524288
  const long nX0 = (long)B * (D0 / 8);    // 1048576
  const long nW1 = (long)D2 * (D1 / 4);   // 524288
  const long nX1 = (long)CH * (D1 / 8);   // 1048576

  // ---- layer 0: merged prep (W0 + Aug0), GEMM at 2 blocks/CU ----
  prep_merge<<<(unsigned)((nW0 + nX0) / 256), 256, 0, stream>>>(
      coef0, sb0, sp0, mask0, W, D0, nW0, x, Aug, D0, nX0);
  {
    dim3 g0(D1 / 256, B / 128);   // (8, 64) = 512 blocks
    gemm128<256><<<g0, 512, 0, stream>>>(Aug, W, bias0, h1, D1, K0);
  }

  // ---- layer 1: merged prep (W1 + Aug1 ch0), GEMM, expand ch1, GEMM ----
  prep_merge<<<(unsigned)((nW1 + nX1) / 256), 256, 0, stream>>>(
      coef1, sb1, sp1, mask1, W, D1, nW1, h1, Aug, D1, nX1);
  {
    dim3 g1(D2 / 128, CH / 128);   // (8, 32) = 256 blocks
    gemm128<128><<<g1, 512, 0, stream>>>(Aug, W, bias1, out, D2, K1);
  }
  expand_aug<<<(unsigned)(nX1 / 256), 256, 0, stream>>>(
      h1 + (size_t)CH * D1, Aug, nX1, D1);
  {
    dim3 g1(D2 / 128, CH / 128);
    gemm128<128><<<g1, 512, 0, stream>>>(Aug, W, bias1,
                                         out + (size_t)CH * D2, D2, K1);
  }
}